// Round 2
// baseline (2794.162 us; speedup 1.0000x reference)
//
#include <hip/hip_runtime.h>
#include <cstdint>
#include <cstddef>

#define B_  2
#define L_  1024
#define DM  1024
#define DI  2048
#define DSN 16
#define DR  64

typedef short          s16x8 __attribute__((ext_vector_type(8)));
typedef float          f32x4 __attribute__((ext_vector_type(4)));
typedef unsigned short u16;
typedef unsigned short u16x4 __attribute__((ext_vector_type(4)));
typedef unsigned int   u32x4 __attribute__((ext_vector_type(4)));

__device__ __forceinline__ u16 f2bf(float f) {
  union { float f; unsigned int u; } v; v.f = f;
  unsigned int u = v.u;
  u += 0x7fffu + ((u >> 16) & 1u);   // round-to-nearest-even
  return (u16)(u >> 16);
}

// ---------------- fp32 -> bf16 convert (vectorized, grid covers n/4) -------
__global__ __launch_bounds__(256) void k_cvt_bf16(const float* __restrict__ in,
                                                  u16* __restrict__ out, int n4) {
  int i = blockIdx.x * 256 + threadIdx.x;
  if (i < n4) {
    f32x4 v = *(const f32x4*)(in + (size_t)i * 4);
    u16x4 o;
    o[0] = f2bf(v[0]); o[1] = f2bf(v[1]); o[2] = f2bf(v[2]); o[3] = f2bf(v[3]);
    *(u16x4*)(out + (size_t)i * 4) = o;
  }
}

// ---------------- embedding gather: one block per (b,l) row ----------------
__global__ __launch_bounds__(256) void k_gather(const int* __restrict__ tok,
                                                const float* __restrict__ emb,
                                                float* __restrict__ h) {
  int row = blockIdx.x;
  int t = tok[row];
  f32x4 v = ((const f32x4*)(emb + (size_t)t * DM))[threadIdx.x];
  ((f32x4*)(h + (size_t)row * DM))[threadIdx.x] = v;
}

// ---------------- rmsnorm (fp32 in) -> bf16 out, one block per row ---------
__global__ __launch_bounds__(256) void k_rmsnorm_bf16(const float* __restrict__ x,
                                                      const float* __restrict__ w,
                                                      u16* __restrict__ out) {
  int row = blockIdx.x;
  int tid = threadIdx.x;
  f32x4 v = ((const f32x4*)(x + (size_t)row * DM))[tid];
  float ss = v[0]*v[0] + v[1]*v[1] + v[2]*v[2] + v[3]*v[3];
  #pragma unroll
  for (int m = 1; m < 64; m <<= 1) ss += __shfl_xor(ss, m);
  __shared__ float red[4];
  if ((tid & 63) == 0) red[tid >> 6] = ss;
  __syncthreads();
  float tot = red[0] + red[1] + red[2] + red[3];
  float sc = rsqrtf(tot * (1.0f / DM) + 1e-5f);
  f32x4 wv = ((const f32x4*)w)[tid];
  u16x4 o;
  o[0] = f2bf(v[0]*sc*wv[0]); o[1] = f2bf(v[1]*sc*wv[1]);
  o[2] = f2bf(v[2]*sc*wv[2]); o[3] = f2bf(v[3]*sc*wv[3]);
  ((u16x4*)(out + (size_t)row * DM))[tid] = o;
}

// ---------------- depthwise causal conv(4) + silu; fp32 + bf16 outputs -----
__global__ __launch_bounds__(256) void k_conv_silu(const float* __restrict__ xz,
                                                   const float* __restrict__ cw,
                                                   const float* __restrict__ cb,
                                                   float* __restrict__ xcf,
                                                   u16* __restrict__ xcbf) {
  int e = blockIdx.x * 256 + threadIdx.x;      // over B*L*DI
  int c = e & (DI - 1);
  int row = e >> 11;                            // b*L + l
  int l = row & (L_ - 1);
  const float* base = xz + (size_t)row * (2 * DI) + c;
  float acc = cb[c];
  float w0 = cw[c*4+0], w1 = cw[c*4+1], w2 = cw[c*4+2], w3 = cw[c*4+3];
  if (l >= 3) acc += base[-3 * (2 * DI)] * w0;
  if (l >= 2) acc += base[-2 * (2 * DI)] * w1;
  if (l >= 1) acc += base[-1 * (2 * DI)] * w2;
  acc += base[0] * w3;
  float s = acc / (1.f + __expf(-acc));
  xcf[e] = s;
  xcbf[e] = f2bf(s);
}

// ---------------- selective scan, fused D-skip + silu(z) gate, bf16 out ----
// block = 16 channels x 16 states; grid = B * (DI/16)
__global__ __launch_bounds__(256) void k_scan(const float* __restrict__ dt,
                                              const float* __restrict__ xcf,
                                              const float* __restrict__ xdbl,
                                              const float* __restrict__ xz,
                                              const float* __restrict__ A_log,
                                              const float* __restrict__ Dsk,
                                              u16* __restrict__ ybf) {
  const int b  = blockIdx.x >> 7;
  const int c0 = (blockIdx.x & 127) << 4;
  const int tid = threadIdx.x;
  const int cl = tid >> 4, s = tid & 15;
  const int c = c0 + cl;
  const float a2  = -__expf(A_log[c * DSN + s]) * 1.4426950408889634f; // A*log2(e)
  const float dsk = Dsk[c];
  __shared__ float s_dt[64][16], s_xc[64][16], s_z[64][16], s_B[64][16], s_C[64][16];
  float hs = 0.f;
  const size_t rowbase = (size_t)b * L_;
  for (int t0 = 0; t0 < L_; t0 += 64) {
    for (int i = tid; i < 1024; i += 256) {
      int tt = i >> 4, cc = i & 15;
      size_t r = rowbase + t0 + tt;
      s_dt[tt][cc] = dt[r * DI + c0 + cc];
      s_xc[tt][cc] = xcf[r * DI + c0 + cc];
      s_z[tt][cc]  = xz[r * (2 * DI) + DI + c0 + cc];
      s_B[tt][cc]  = xdbl[r * 96 + 64 + cc];
      s_C[tt][cc]  = xdbl[r * 96 + 80 + cc];
    }
    __syncthreads();
    #pragma unroll 4
    for (int tt = 0; tt < 64; ++tt) {
      float dtv = s_dt[tt][cl];
      float xv  = s_xc[tt][cl];
      float Bv  = s_B[tt][s];
      float Cv  = s_C[tt][s];
      float dA = exp2f(dtv * a2);
      hs = dA * hs + dtv * xv * Bv;
      float yv = hs * Cv;
      yv += __shfl_xor(yv, 1);
      yv += __shfl_xor(yv, 2);
      yv += __shfl_xor(yv, 4);
      yv += __shfl_xor(yv, 8);
      if (s == 0) {
        float zv = s_z[tt][cl];
        float yo = (yv + xv * dsk) * (zv / (1.f + __expf(-zv)));
        ybf[(rowbase + t0 + tt) * DI + c] = f2bf(yo);
      }
    }
    __syncthreads();
  }
}

// ---------------- bf16 MFMA NT-GEMM: C(MxN) = A(MxK) . W(NxK)^T ------------
// EPI: 0 = plain fp32 store; 1 = +=residual(C preloaded); 2 = softplus(v+bias[n]);
//      3 = plain store + bf16 aux for n<DR (x_proj -> dtr)
template <int WM, int WN, int EPI>
__global__ __launch_bounds__(256) void k_gemm(const u16* __restrict__ A,
                                              const u16* __restrict__ W,
                                              float* __restrict__ C,
                                              u16* __restrict__ aux,
                                              const float* __restrict__ bias,
                                              int M, int N, int K) {
  constexpr int BM = 32 * WM, BN = 32 * WN, BK = 32;
  __shared__ __align__(16) u16 As[BM * BK];
  __shared__ __align__(16) u16 Bs[BN * BK];
  const int tid = threadIdx.x;
  const int m0 = blockIdx.y * BM, n0 = blockIdx.x * BN;
  const int wave = tid >> 6, lane = tid & 63;
  const int wm = wave & 1, wn = wave >> 1;
  const int l15 = lane & 15, quad = lane >> 4;

  f32x4 acc[WM][WN];
  #pragma unroll
  for (int i = 0; i < WM; ++i)
    #pragma unroll
    for (int j = 0; j < WN; ++j)
      acc[i][j] = f32x4{0.f, 0.f, 0.f, 0.f};

  for (int k0 = 0; k0 < K; k0 += BK) {
    for (int i = tid; i < BM * 4; i += 256) {
      int r = i >> 2, cc = i & 3;
      *(u32x4*)(As + r * BK + cc * 8) =
          *(const u32x4*)(A + (size_t)(m0 + r) * K + k0 + cc * 8);
    }
    for (int i = tid; i < BN * 4; i += 256) {
      int r = i >> 2, cc = i & 3;
      *(u32x4*)(Bs + r * BK + cc * 8) =
          *(const u32x4*)(W + (size_t)(n0 + r) * K + k0 + cc * 8);
    }
    __syncthreads();
    s16x8 af[WM], bfv[WN];
    #pragma unroll
    for (int i = 0; i < WM; ++i)
      af[i] = *(const s16x8*)(As + (wm * WM * 16 + i * 16 + l15) * BK + quad * 8);
    #pragma unroll
    for (int j = 0; j < WN; ++j)
      bfv[j] = *(const s16x8*)(Bs + (wn * WN * 16 + j * 16 + l15) * BK + quad * 8);
    #pragma unroll
    for (int i = 0; i < WM; ++i)
      #pragma unroll
      for (int j = 0; j < WN; ++j)
        acc[i][j] = __builtin_amdgcn_mfma_f32_16x16x32_bf16(af[i], bfv[j], acc[i][j], 0, 0, 0);
    __syncthreads();
  }

  #pragma unroll
  for (int i = 0; i < WM; ++i) {
    #pragma unroll
    for (int j = 0; j < WN; ++j) {
      int mb = m0 + wm * WM * 16 + i * 16 + quad * 4;
      int nb = n0 + wn * WN * 16 + j * 16 + l15;
      #pragma unroll
      for (int r = 0; r < 4; ++r) {
        size_t idx = (size_t)(mb + r) * N + nb;
        float v = acc[i][j][r];
        if constexpr (EPI == 1) v += C[idx];
        if constexpr (EPI == 2) {
          v += bias[nb];
          v = (v > 20.f) ? v : log1pf(__expf(v));
        }
        C[idx] = v;
        if constexpr (EPI == 3) {
          if (nb < DR) aux[(size_t)(mb + r) * DR + nb] = f2bf(v);
        }
      }
    }
  }
}

// ---------------------------------------------------------------------------
extern "C" void kernel_launch(void* const* d_in, const int* in_sizes, int n_in,
                              void* d_out, int out_size, void* d_ws, size_t ws_size,
                              hipStream_t stream) {
  const int*   tokens = (const int*)d_in[0];
  const float* embed  = (const float*)d_in[1];
  const float* norm_w = (const float*)d_in[2];
  const float* in_w   = (const float*)d_in[3];
  const float* conv_w = (const float*)d_in[4];
  const float* conv_b = (const float*)d_in[5];
  const float* xp_w   = (const float*)d_in[6];
  const float* dt_w   = (const float*)d_in[7];
  const float* dt_b   = (const float*)d_in[8];
  const float* A_log  = (const float*)d_in[9];
  const float* D_skip = (const float*)d_in[10];
  const float* out_w  = (const float*)d_in[11];
  const float* fnw    = (const float*)d_in[12];
  float* logits = (float*)d_out;

  char* ws = (char*)d_ws;
  size_t off = 0;
  auto alloc = [&](size_t bytes) -> void* {
    void* p = ws + off;
    off = (off + bytes + 255) & ~(size_t)255;
    return p;
  };
  const size_t R = (size_t)B_ * L_;                 // 2048 rows
  float* h     = (float*)alloc(R * DM * 4);         //  8 MB
  u16*   xbf   = (u16*)  alloc(R * DM * 2);         //  4 MB
  float* xz    = (float*)alloc(R * 2 * DI * 4);     // 32 MB
  float* xcf   = (float*)alloc(R * DI * 4);         // 16 MB
  u16*   xcbf  = (u16*)  alloc(R * DI * 2);         //  8 MB
  float* xdbl  = (float*)alloc(R * 96 * 4);         // .75 MB
  u16*   dtrbf = (u16*)  alloc(R * DR * 2);         // .25 MB
  float* dtv   = (float*)alloc(R * DI * 4);         // 16 MB
  u16*   ybf   = (u16*)  alloc(R * DI * 2);         //  8 MB
  u16*   w_in  = (u16*)  alloc((size_t)2 * DI * DM * 2);  //  8 MB (per-layer, reused)
  u16*   w_out = (u16*)  alloc((size_t)DM * DI * 2);      //  4 MB
  u16*   w_xp  = (u16*)  alloc((size_t)96 * DI * 2);      // .4 MB
  u16*   w_dt  = (u16*)  alloc((size_t)DI * DR * 2);      // .25 MB
  u16*   embbf = (u16*)  alloc(32000ull * DM * 2);        // 62.5 MB
  // total ~169 MB; guard against a smaller-than-expected workspace so an
  // undersized ws shows up as a clean absmax failure, not a container crash.
  if (off > ws_size) return;

  auto cvt = [&](const float* src, u16* dst, size_t n) {
    int n4 = (int)(n / 4);
    k_cvt_bf16<<<(n4 + 255) / 256, 256, 0, stream>>>(src, dst, n4);
  };
  cvt(embed, embbf, 32000ull * DM);

  k_gather<<<(int)R, 256, 0, stream>>>(tokens, embed, h);

  for (int i = 0; i < 4; ++i) {
    cvt(in_w  + (size_t)i * 2 * DI * DM, w_in,  (size_t)2 * DI * DM);
    cvt(out_w + (size_t)i * DM * DI,     w_out, (size_t)DM * DI);
    cvt(xp_w  + (size_t)i * 96 * DI,     w_xp,  (size_t)96 * DI);
    cvt(dt_w  + (size_t)i * DI * DR,     w_dt,  (size_t)DI * DR);

    k_rmsnorm_bf16<<<(int)R, 256, 0, stream>>>(h, norm_w + i * DM, xbf);
    // in_proj: (2048,1024) x (4096,1024)^T -> xz (2048,4096)
    k_gemm<4, 4, 0><<<dim3(2 * DI / 128, (int)R / 128), 256, 0, stream>>>(
        xbf, w_in, xz, nullptr, nullptr, (int)R, 2 * DI, DM);
    k_conv_silu<<<(int)(R * DI) / 256, 256, 0, stream>>>(
        xz, conv_w + i * DI * 4, conv_b + i * DI, xcf, xcbf);
    // x_proj: (2048,2048) x (96,2048)^T -> xdbl (2048,96), aux dtr bf16
    k_gemm<2, 3, 3><<<dim3(1, (int)R / 64), 256, 0, stream>>>(
        xcbf, w_xp, xdbl, dtrbf, nullptr, (int)R, 96, DI);
    // dt_proj: (2048,64) x (2048,64)^T -> softplus(.+dt_b) -> dt (2048,2048)
    k_gemm<4, 4, 2><<<dim3(DI / 128, (int)R / 128), 256, 0, stream>>>(
        dtrbf, w_dt, dtv, nullptr, dt_b + i * DI, (int)R, DI, DR);
    k_scan<<<B_ * (DI / 16), 256, 0, stream>>>(
        dtv, xcf, xdbl, xz, A_log + i * DI * DSN, D_skip + i * DI, ybf);
    // out_proj: (2048,2048) x (1024,2048)^T, residual add in-place into h
    k_gemm<4, 4, 1><<<dim3(DM / 128, (int)R / 128), 256, 0, stream>>>(
        ybf, w_out, h, nullptr, nullptr, (int)R, DM, DI);
  }
  k_rmsnorm_bf16<<<(int)R, 256, 0, stream>>>(h, fnw, xbf);
  // logits: (2048,1024) x (32000,1024)^T -> d_out (2048,32000)
  k_gemm<4, 4, 0><<<dim3(32000 / 128, (int)R / 128), 256, 0, stream>>>(
      xbf, embbf, logits, nullptr, nullptr, (int)R, 32000, DM);
}